// Round 11
// baseline (211.693 us; speedup 1.0000x reference)
//
#include <hip/hip_runtime.h>
#include <hip/hip_bf16.h>
#include <cmath>

#define D 256
#define NH 8
#define B 2
#define EPW 4       // edges per wave
#define NBKMAX 1024 // max buckets
#define NCHMAX 512  // max sort chunks
#define SBLK 1024   // edges per sort chunk
#define SUBCAP 2048 // max bucket segment for in-LDS subsort (perf-only cap)

#if defined(__has_builtin)
#  if __has_builtin(__builtin_amdgcn_fdot2_f32_bf16)
#    define USE_BF16_DOT 1
#  else
#    define USE_BF16_DOT 0
#  endif
#else
#  define USE_BF16_DOT 0
#endif

#if USE_BF16_DOT
typedef __bf16 bf16x2 __attribute__((ext_vector_type(2)));
#endif

__device__ inline unsigned short f2bf(float f) {
    unsigned u = __float_as_uint(f);
    unsigned r = u + 0x7FFFu + ((u >> 16) & 1u);   // RNE
    return (unsigned short)(r >> 16);
}

// 16-elem bf16 dot (one uint4 pair) -- R7-verbatim (HW-validated).
__device__ inline float dot16(const uint4& a, const uint4& b) {
    float p = 0.f;
#if USE_BF16_DOT
    const bf16x2* av = (const bf16x2*)&a;
    const bf16x2* bv = (const bf16x2*)&b;
    #pragma unroll
    for (int w = 0; w < 4; ++w)
        p = __builtin_amdgcn_fdot2_f32_bf16(av[w], bv[w], p, false);
#else
    const unsigned* aw = (const unsigned*)&a;
    const unsigned* bw = (const unsigned*)&b;
    #pragma unroll
    for (int w = 0; w < 4; ++w) {
        float al = __uint_as_float(aw[w] << 16);
        float ah = __uint_as_float(aw[w] & 0xFFFF0000u);
        float bl = __uint_as_float(bw[w] << 16);
        float bh = __uint_as_float(bw[w] & 0xFFFF0000u);
        p = fmaf(al, bl, p);
        p = fmaf(ah, bh, p);
    }
#endif
    return p;
}

// Sort key. R11: back to single-level e0-bucket (nb1==1 -> key = e0/sdiv,
// sdiv=64). R10's e1-minor key cut FETCH 150->126MB with ZERO time change
// -> volume isn't the pipe; L2 REQUEST COUNT is. Exact-e0 runs (via
// k_subsort) turn q re-loads into L1 hits, removing ~half the L2 requests.
__device__ inline int edge_key(int e0, int e1, int sdiv, int nb1) {
    int kminor = (nb1 > 1) ? (e1 >> 8) : 0;
    return (e0 / sdiv) * nb1 + kminor;
}

// K0: fp32 [bb][node][d] -> packed bf16 [node][bb][d]; also zeroes seg.
__global__ __launch_bounds__(256) void k_conv(
    const float* __restrict__ q, const float* __restrict__ k,
    uint4* __restrict__ qc, uint4* __restrict__ kc,
    float* __restrict__ seg, int segN, int n)
{
    int tid    = blockIdx.x * blockDim.x + threadIdx.x;
    int stride = gridDim.x * blockDim.x;
    for (int i = tid; i < segN; i += stride) seg[i] = 0.f;
    int total = n * B * 32;
    for (int i = tid; i < total; i += stride) {
        int c   = i & 31;
        int row = i >> 5;                 // bb*n + node
        int bb  = (row >= n) ? 1 : 0;
        int node = row - bb * n;
        const float4* qs = (const float4*)(q + ((size_t)row << 8)) + (c << 1);
        const float4* ks = (const float4*)(k + ((size_t)row << 8)) + (c << 1);
        float4 a0 = qs[0], a1 = qs[1];
        float4 b0 = ks[0], b1 = ks[1];
        uint4 pa, pb;
        pa.x = (unsigned)f2bf(a0.x) | ((unsigned)f2bf(a0.y) << 16);
        pa.y = (unsigned)f2bf(a0.z) | ((unsigned)f2bf(a0.w) << 16);
        pa.z = (unsigned)f2bf(a1.x) | ((unsigned)f2bf(a1.y) << 16);
        pa.w = (unsigned)f2bf(a1.z) | ((unsigned)f2bf(a1.w) << 16);
        pb.x = (unsigned)f2bf(b0.x) | ((unsigned)f2bf(b0.y) << 16);
        pb.y = (unsigned)f2bf(b0.z) | ((unsigned)f2bf(b0.w) << 16);
        pb.z = (unsigned)f2bf(b1.x) | ((unsigned)f2bf(b1.y) << 16);
        pb.w = (unsigned)f2bf(b1.z) | ((unsigned)f2bf(b1.w) << 16);
        size_t dst = ((size_t)node * B + bb) * 32 + c;
        qc[dst] = pa;
        kc[dst] = pb;
    }
}

// ---- Atomic-free counting sort (R6/R10 structure, proven). ----

__global__ __launch_bounds__(256) void k_hist2(
    const int* __restrict__ e, int* __restrict__ bh, int m, int nbk,
    int sdiv, int nb1)
{
    __shared__ int lh[NBKMAX];
    int b = blockIdx.x;
    int start = b * SBLK, end = min(m, start + SBLK);
    for (int t = threadIdx.x; t < nbk; t += 256) lh[t] = 0;
    __syncthreads();
    for (int j = start + threadIdx.x; j < end; j += 256)
        atomicAdd(&lh[edge_key(e[j], e[m + j], sdiv, nb1)], 1);
    __syncthreads();
    for (int t = threadIdx.x; t < nbk; t += 256)
        bh[(size_t)b * nbk + t] = lh[t];
}

__global__ __launch_bounds__(NCHMAX) void k_colscan(
    int* __restrict__ bh, int* __restrict__ tot, int nch, int nbk)
{
    __shared__ int tmp[NCHMAX];
    int t = blockIdx.x;           // bucket
    int b = threadIdx.x;          // chunk
    int v = (b < nch) ? bh[(size_t)b * nbk + t] : 0;
    tmp[b] = v;
    __syncthreads();
    for (int off = 1; off < NCHMAX; off <<= 1) {   // uniform control flow
        int u = (b >= off) ? tmp[b - off] : 0;
        __syncthreads();
        tmp[b] += u;
        __syncthreads();
    }
    if (b < nch) bh[(size_t)b * nbk + t] = tmp[b] - v;  // excl. column prefix
    if (b == NCHMAX - 1) tot[t] = tmp[b];               // column total
}

__global__ __launch_bounds__(NBKMAX) void k_basescan(
    const int* __restrict__ tot, int* __restrict__ base, int nbk)
{
    __shared__ int tmp[NBKMAX];
    int t = threadIdx.x;
    int v = (t < nbk) ? tot[t] : 0;
    tmp[t] = v;
    __syncthreads();
    for (int off = 1; off < NBKMAX; off <<= 1) {
        int u = (t >= off) ? tmp[t - off] : 0;
        __syncthreads();
        tmp[t] += u;
        __syncthreads();
    }
    if (t < nbk) base[t] = tmp[t] - v;
}

__global__ __launch_bounds__(256) void k_scatter2(
    const int* __restrict__ e, const int* __restrict__ r,
    const int* __restrict__ bh, const int* __restrict__ base,
    int4* __restrict__ perm, int m, int nbk, int sdiv, int nb1)
{
    __shared__ int cur[NBKMAX];
    int b = blockIdx.x;
    int start = b * SBLK, end = min(m, start + SBLK);
    for (int t = threadIdx.x; t < nbk; t += 256)
        cur[t] = bh[(size_t)b * nbk + t] + base[t];
    __syncthreads();
    for (int j = start + threadIdx.x; j < end; j += 256) {
        int e0 = e[j], e1 = e[m + j];
        int pos = atomicAdd(&cur[edge_key(e0, e1, sdiv, nb1)], 1);  // LDS atomic
        perm[pos] = make_int4(e0, e1, r[j], j);
    }
}

// R11-NEW: in-LDS counting sort of each bucket segment by exact e0
// (sub-bucket = e0 & 63). Makes runs of IDENTICAL e0 -> the 4 q-loads per
// wave (and across the block's waves) hit the same addresses -> L1 hits,
// never reaching L2. Order is correctness-irrelevant (orig j carried), so
// len>SUBCAP safely no-ops and any ordering bug is perf-only.
__global__ __launch_bounds__(256) void k_subsort(
    int4* __restrict__ perm, const int* __restrict__ base, int m, int nbk)
{
    __shared__ int4 buf[SUBCAP];
    __shared__ int hist[64], off[64];
    int t = blockIdx.x;
    int start = base[t];
    int end   = (t + 1 < nbk) ? base[t + 1] : m;
    int len   = end - start;
    if (len <= 1 || len > SUBCAP) return;   // uniform branch, before barriers
    for (int i = threadIdx.x; i < len; i += 256) buf[i] = perm[start + i];
    if (threadIdx.x < 64) hist[threadIdx.x] = 0;
    __syncthreads();
    for (int i = threadIdx.x; i < len; i += 256)
        atomicAdd(&hist[buf[i].x & 63], 1);
    __syncthreads();
    if (threadIdx.x == 0) {                 // 64-elem serial scan, trivial
        int run = 0;
        #pragma unroll
        for (int i = 0; i < 64; ++i) { off[i] = run; run += hist[i]; }
    }
    __syncthreads();
    for (int i = threadIdx.x; i < len; i += 256) {
        int pos = atomicAdd(&off[buf[i].x & 63], 1);
        perm[start + pos] = buf[i];
    }
}

// K1: gather + scores + exp + segment atomicAdd over sorted edges.
// Body R7-VERBATIM (the only HW-validated load/consume pattern).
__global__ __launch_bounds__(256) void k_scores_perm(
    const ushort* __restrict__ qc, const ushort* __restrict__ kc,
    const int4* __restrict__ perm,
    float* __restrict__ s, float* __restrict__ seg, int m, int do_swz)
{
    int bid = blockIdx.x;
    if (do_swz) {                       // XCD-chunked (bijective: grid%8==0)
        int nb8 = gridDim.x >> 3;
        bid = (bid & 7) * nb8 + (bid >> 3);
    }
    int wave = (bid << 2) + (threadIdx.x >> 6);
    int lane = threadIdx.x & 63;
    int j0 = wave * EPW;
    if (j0 >= m) return;

    int rr[EPW], jo[EPW];
    uint4 qa[EPW], kb[EPW];
    #pragma unroll
    for (int t = 0; t < EPW; ++t) {
        int j = j0 + t;
        int4 p = (j < m) ? perm[j] : make_int4(0, 0, 0, -1);
        rr[t] = p.z;
        jo[t] = p.w;   // original edge index (or -1 = inactive)
        qa[t] = ((const uint4*)(qc + (size_t)p.x * (B * D)))[lane];
        kb[t] = ((const uint4*)(kc + (size_t)p.y * (B * D)))[lane];
    }
    __builtin_amdgcn_sched_barrier(0);

    #pragma unroll
    for (int t = 0; t < EPW; ++t) {
        float p = dot16(qa[t], kb[t]);
        p += __shfl_xor(p, 1);
        p += __shfl_xor(p, 2);
        float ex = __expf(p * 0.0625f);     // /sqrt(256), no max shift
        if ((lane & 3) == 0 && jo[t] >= 0) {
            int bb = lane >> 5;
            int h  = (lane >> 2) & 7;
            s[((size_t)bb * m + jo[t]) * NH + h] = ex;
            atomicAdd(&seg[((size_t)rr[t] * B + bb) * NH + h], ex);
        }
    }
}

// K1-direct: original-order fallback (R7-verbatim).
__global__ __launch_bounds__(256) void k_scores_fused(
    const ushort* __restrict__ qc, const ushort* __restrict__ kc,
    const int* __restrict__ e, const int* __restrict__ r,
    float* __restrict__ s, float* __restrict__ seg, int m)
{
    int wave = (int)((blockIdx.x * blockDim.x + threadIdx.x) >> 6);
    int lane = threadIdx.x & 63;
    int j0 = wave * EPW;
    if (j0 >= m) return;

    int e0[EPW], e1[EPW], rr[EPW];
    #pragma unroll
    for (int t = 0; t < EPW; ++t) {
        int j = j0 + t;
        int ok = (j < m);
        e0[t] = ok ? e[j]     : 0;
        e1[t] = ok ? e[m + j] : 0;
        rr[t] = ok ? r[j]     : 0;
    }
    uint4 qa[EPW], kb[EPW];
    #pragma unroll
    for (int t = 0; t < EPW; ++t) {
        qa[t] = ((const uint4*)(qc + (size_t)e0[t] * (B * D)))[lane];
        kb[t] = ((const uint4*)(kc + (size_t)e1[t] * (B * D)))[lane];
    }
    __builtin_amdgcn_sched_barrier(0);
    #pragma unroll
    for (int t = 0; t < EPW; ++t) {
        float p = dot16(qa[t], kb[t]);
        p += __shfl_xor(p, 1);
        p += __shfl_xor(p, 2);
        float ex = __expf(p * 0.0625f);
        if ((lane & 3) == 0 && (j0 + t) < m) {
            int bb = lane >> 5;
            int h  = (lane >> 2) & 7;
            s[((size_t)bb * m + (j0 + t)) * NH + h] = ex;
            atomicAdd(&seg[((size_t)rr[t] * B + bb) * NH + h], ex);
        }
    }
}

// fp32 fallback (ws too small for bf16 buffers).
__global__ __launch_bounds__(256) void k_scores_fused_f32(
    const float* __restrict__ q, const float* __restrict__ k,
    const int* __restrict__ e, const int* __restrict__ r,
    float* __restrict__ s, float* __restrict__ seg, int n, int m)
{
    int wave = (int)((blockIdx.x * blockDim.x + threadIdx.x) >> 6);
    int lane = threadIdx.x & 63;
    int j0 = wave * EPW;
    if (j0 >= m) return;
    int e0[EPW], e1[EPW], rr[EPW];
    #pragma unroll
    for (int t = 0; t < EPW; ++t) {
        int j = j0 + t; int ok = (j < m);
        e0[t] = ok ? e[j] : 0; e1[t] = ok ? e[m + j] : 0; rr[t] = ok ? r[j] : 0;
    }
    float4 qa[B][EPW], kb[B][EPW];
    #pragma unroll
    for (int bb = 0; bb < B; ++bb)
        #pragma unroll
        for (int t = 0; t < EPW; ++t) {
            qa[bb][t] = ((const float4*)(q + ((size_t)bb * n + e0[t]) * D))[lane];
            kb[bb][t] = ((const float4*)(k + ((size_t)bb * n + e1[t]) * D))[lane];
        }
    #pragma unroll
    for (int bb = 0; bb < B; ++bb)
        #pragma unroll
        for (int t = 0; t < EPW; ++t) {
            float4 A = qa[bb][t], K4 = kb[bb][t];
            float p = A.x * K4.x + A.y * K4.y + A.z * K4.z + A.w * K4.w;
            p += __shfl_xor(p, 1); p += __shfl_xor(p, 2); p += __shfl_xor(p, 4);
            float ex = __expf(p * 0.0625f);
            if ((lane & 7) == 0 && (j0 + t) < m) {
                int h = lane >> 3;
                s[((size_t)bb * m + (j0 + t)) * NH + h] = ex;
                atomicAdd(&seg[((size_t)rr[t] * B + bb) * NH + h], ex);
            }
        }
}

// K2: one thread per (bb, edge). out = ex / (seg + eps), float4 in-place.
__global__ __launch_bounds__(256) void k_norm(
    float* __restrict__ s, const int* __restrict__ r,
    const float* __restrict__ seg, int m)
{
    int i = blockIdx.x * blockDim.x + threadIdx.x;
    int total = B * m;
    if (i >= total) return;
    int bb = (i >= m) ? 1 : 0;
    int j  = i - bb * m;
    const float4* sg = (const float4*)(seg + ((size_t)r[j] * B + bb) * NH);
    float4* sp = (float4*)(s + (size_t)i * NH);
    float4 d0 = sg[0], d1 = sg[1];
    float4 x0 = sp[0], x1 = sp[1];
    x0.x = __fdividef(x0.x, d0.x + 1e-16f);
    x0.y = __fdividef(x0.y, d0.y + 1e-16f);
    x0.z = __fdividef(x0.z, d0.z + 1e-16f);
    x0.w = __fdividef(x0.w, d0.w + 1e-16f);
    x1.x = __fdividef(x1.x, d1.x + 1e-16f);
    x1.y = __fdividef(x1.y, d1.y + 1e-16f);
    x1.z = __fdividef(x1.z, d1.z + 1e-16f);
    x1.w = __fdividef(x1.w, d1.w + 1e-16f);
    sp[0] = x0; sp[1] = x1;
}

extern "C" void kernel_launch(void* const* d_in, const int* in_sizes, int n_in,
                              void* d_out, int out_size, void* d_ws, size_t ws_size,
                              hipStream_t stream) {
    const float* q = (const float*)d_in[0];
    const float* k = (const float*)d_in[1];
    const int*   e = (const int*)d_in[2];
    const int*   r = (const int*)d_in[3];
    float* s = (float*)d_out;

    int n = in_sizes[0] / (B * D);          // 20000
    int m = in_sizes[3];                    // 320000
    int sdiv = 64;                          // 64 nodes per bucket
    int nb1  = 1;                           // single-level key (R11)
    int nbk  = (n + 63) >> 6;               // 313 buckets
    int nch  = (m + SBLK - 1) / SBLK;       // 313 chunks
    int segN = n * B * NH;                  // 320000 floats

    // ws layout: seg | qc | kc | perm | bh | tot | base
    size_t seg_bytes  = (size_t)segN * sizeof(float);                // 1.28 MB
    size_t row_bytes  = (size_t)n * B * D * sizeof(unsigned short);  // 20.48 MB
    size_t perm_bytes = (size_t)m * sizeof(int4);                    // 5.12 MB
    size_t bh_bytes   = (size_t)nch * nbk * sizeof(int);             // ~0.4 MB
    size_t tb_bytes   = 2 * NBKMAX * sizeof(int);                    // 8 KB

    float*  seg  = (float*)d_ws;
    ushort* qc   = (ushort*)((char*)d_ws + seg_bytes);
    ushort* kc   = (ushort*)((char*)d_ws + seg_bytes + row_bytes);
    int4*   perm = (int4*)((char*)d_ws + seg_bytes + 2 * row_bytes);
    int*    bh   = (int*)((char*)d_ws + seg_bytes + 2 * row_bytes + perm_bytes);
    int*    tot  = (int*)((char*)bh + bh_bytes);
    int*    base = tot + NBKMAX;

    bool use_bf16 = ws_size >= (seg_bytes + 2 * row_bytes);
    bool use_sort = use_bf16 && nbk <= NBKMAX && nch <= NCHMAX &&
                    ws_size >= (seg_bytes + 2 * row_bytes + perm_bytes +
                                bh_bytes + tb_bytes);

    int nblocks = (B * m + 255) / 256;
    int nwaves  = (m + EPW - 1) / EPW;
    int sblocks = (nwaves + 3) / 4;

    if (use_bf16) {
        int cblocks = (n * B * 32 + 255) / 256;
        k_conv<<<cblocks, 256, 0, stream>>>(q, k, (uint4*)qc, (uint4*)kc,
                                            seg, segN, n);
        if (use_sort) {
            k_hist2<<<nch, 256, 0, stream>>>(e, bh, m, nbk, sdiv, nb1);
            k_colscan<<<nbk, NCHMAX, 0, stream>>>(bh, tot, nch, nbk);
            k_basescan<<<1, NBKMAX, 0, stream>>>(tot, base, nbk);
            k_scatter2<<<nch, 256, 0, stream>>>(e, r, bh, base, perm, m, nbk,
                                                sdiv, nb1);
            k_subsort<<<nbk, 256, 0, stream>>>(perm, base, m, nbk);
            int do_swz = (sblocks % 8 == 0) ? 1 : 0;
            k_scores_perm<<<sblocks, 256, 0, stream>>>(qc, kc, perm, s, seg, m, do_swz);
        } else {
            k_scores_fused<<<sblocks, 256, 0, stream>>>(qc, kc, e, r, s, seg, m);
        }
    } else {
        hipMemsetAsync(d_ws, 0, seg_bytes, stream);
        k_scores_fused_f32<<<sblocks, 256, 0, stream>>>(q, k, e, r, s, seg, n, m);
    }
    k_norm<<<nblocks, 256, 0, stream>>>(s, r, seg, m);
}

// Round 12
// 206.070 us; speedup vs baseline: 1.0273x; 1.0273x over previous
//
#include <hip/hip_runtime.h>
#include <hip/hip_bf16.h>
#include <cmath>

#define D 256
#define NH 8
#define B 2
#define EPW 4       // edges per wave
#define SSH 5       // bucket = e0 >> 5 (32 nodes = 32KB q-window = L1-sized)
#define NBKMAX 1024 // max buckets (scan width; 256 threads x 4)
#define NCHMAX 512  // max sort chunks
#define SBLK 1024   // edges per sort chunk

#if defined(__has_builtin)
#  if __has_builtin(__builtin_amdgcn_fdot2_f32_bf16)
#    define USE_BF16_DOT 1
#  else
#    define USE_BF16_DOT 0
#  endif
#else
#  define USE_BF16_DOT 0
#endif

#if USE_BF16_DOT
typedef __bf16 bf16x2 __attribute__((ext_vector_type(2)));
#endif

__device__ inline unsigned short f2bf(float f) {
    unsigned u = __float_as_uint(f);
    unsigned r = u + 0x7FFFu + ((u >> 16) & 1u);   // RNE
    return (unsigned short)(r >> 16);
}

// 16-elem bf16 dot (one uint4 pair) -- R7-verbatim (HW-validated).
__device__ inline float dot16(const uint4& a, const uint4& b) {
    float p = 0.f;
#if USE_BF16_DOT
    const bf16x2* av = (const bf16x2*)&a;
    const bf16x2* bv = (const bf16x2*)&b;
    #pragma unroll
    for (int w = 0; w < 4; ++w)
        p = __builtin_amdgcn_fdot2_f32_bf16(av[w], bv[w], p, false);
#else
    const unsigned* aw = (const unsigned*)&a;
    const unsigned* bw = (const unsigned*)&b;
    #pragma unroll
    for (int w = 0; w < 4; ++w) {
        float al = __uint_as_float(aw[w] << 16);
        float ah = __uint_as_float(aw[w] & 0xFFFF0000u);
        float bl = __uint_as_float(bw[w] << 16);
        float bh = __uint_as_float(bw[w] & 0xFFFF0000u);
        p = fmaf(al, bl, p);
        p = fmaf(ah, bh, p);
    }
#endif
    return p;
}

// K0: fp32 [bb][node][d] -> packed bf16 [node][bb][d]; also zeroes seg.
__global__ __launch_bounds__(256) void k_conv(
    const float* __restrict__ q, const float* __restrict__ k,
    uint4* __restrict__ qc, uint4* __restrict__ kc,
    float* __restrict__ seg, int segN, int n)
{
    int tid    = blockIdx.x * blockDim.x + threadIdx.x;
    int stride = gridDim.x * blockDim.x;
    for (int i = tid; i < segN; i += stride) seg[i] = 0.f;
    int total = n * B * 32;
    for (int i = tid; i < total; i += stride) {
        int c   = i & 31;
        int row = i >> 5;                 // bb*n + node
        int bb  = (row >= n) ? 1 : 0;
        int node = row - bb * n;
        const float4* qs = (const float4*)(q + ((size_t)row << 8)) + (c << 1);
        const float4* ks = (const float4*)(k + ((size_t)row << 8)) + (c << 1);
        float4 a0 = qs[0], a1 = qs[1];
        float4 b0 = ks[0], b1 = ks[1];
        uint4 pa, pb;
        pa.x = (unsigned)f2bf(a0.x) | ((unsigned)f2bf(a0.y) << 16);
        pa.y = (unsigned)f2bf(a0.z) | ((unsigned)f2bf(a0.w) << 16);
        pa.z = (unsigned)f2bf(a1.x) | ((unsigned)f2bf(a1.y) << 16);
        pa.w = (unsigned)f2bf(a1.z) | ((unsigned)f2bf(a1.w) << 16);
        pb.x = (unsigned)f2bf(b0.x) | ((unsigned)f2bf(b0.y) << 16);
        pb.y = (unsigned)f2bf(b0.z) | ((unsigned)f2bf(b0.w) << 16);
        pb.z = (unsigned)f2bf(b1.x) | ((unsigned)f2bf(b1.y) << 16);
        pb.w = (unsigned)f2bf(b1.z) | ((unsigned)f2bf(b1.w) << 16);
        size_t dst = ((size_t)node * B + bb) * 32 + c;
        qc[dst] = pa;
        kc[dst] = pb;
    }
}

// ---- Atomic-free counting sort (R6 machinery; R12: 32-node buckets,
// basescan folded into scatter -> one fewer dispatch). ----

// A: chunk b's bucket histogram -> bh[b*nbk + t].
__global__ __launch_bounds__(256) void k_hist2(
    const int* __restrict__ e, int* __restrict__ bh, int m, int nbk)
{
    __shared__ int lh[NBKMAX];
    int b = blockIdx.x;
    int start = b * SBLK, end = min(m, start + SBLK);
    for (int t = threadIdx.x; t < nbk; t += 256) lh[t] = 0;
    __syncthreads();
    for (int j = start + threadIdx.x; j < end; j += 256)
        atomicAdd(&lh[e[j] >> SSH], 1);
    __syncthreads();
    for (int t = threadIdx.x; t < nbk; t += 256)
        bh[(size_t)b * nbk + t] = lh[t];
}

// B: per-bucket column scan -> excl. prefixes in bh + column total in tot.
__global__ __launch_bounds__(NCHMAX) void k_colscan(
    int* __restrict__ bh, int* __restrict__ tot, int nch, int nbk)
{
    __shared__ int tmp[NCHMAX];
    int t = blockIdx.x;           // bucket
    int b = threadIdx.x;          // chunk
    int v = (b < nch) ? bh[(size_t)b * nbk + t] : 0;
    tmp[b] = v;
    __syncthreads();
    for (int off = 1; off < NCHMAX; off <<= 1) {   // uniform control flow
        int u = (b >= off) ? tmp[b - off] : 0;
        __syncthreads();
        tmp[b] += u;
        __syncthreads();
    }
    if (b < nch) bh[(size_t)b * nbk + t] = tmp[b] - v;  // excl. column prefix
    if (b == NCHMAX - 1) tot[t] = tmp[b];               // column total
}

// C: scatter. Each block first derives base[] from tot via an in-LDS
// 1024-wide exclusive scan (strip-of-4 + Hillis-Steele over 256 partials;
// ~1us, replaces the k_basescan dispatch), then scatters its chunk via
// LDS cursors. perm[pos] = {e0, e1, r, orig_j}; order within bucket is
// correctness-irrelevant (orig j carried).
__global__ __launch_bounds__(256) void k_scatter2(
    const int* __restrict__ e, const int* __restrict__ r,
    const int* __restrict__ bh, const int* __restrict__ tot,
    int4* __restrict__ perm, int m, int nbk)
{
    __shared__ int tl[NBKMAX];
    __shared__ int tp[256];
    int b = blockIdx.x;
    int tid = threadIdx.x;
    for (int i = tid; i < NBKMAX; i += 256)
        tl[i] = (i < nbk) ? tot[i] : 0;
    __syncthreads();
    // strip-of-4 exclusive prefix + strip sum
    int s0 = tl[tid * 4 + 0], s1 = tl[tid * 4 + 1];
    int s2 = tl[tid * 4 + 2], s3 = tl[tid * 4 + 3];
    tl[tid * 4 + 0] = 0;
    tl[tid * 4 + 1] = s0;
    tl[tid * 4 + 2] = s0 + s1;
    tl[tid * 4 + 3] = s0 + s1 + s2;
    int v = s0 + s1 + s2 + s3;
    tp[tid] = v;
    __syncthreads();
    for (int off = 1; off < 256; off <<= 1) {      // uniform control flow
        int u = (tid >= off) ? tp[tid - off] : 0;
        __syncthreads();
        tp[tid] += u;
        __syncthreads();
    }
    int stripbase = tp[tid] - v;                   // exclusive strip prefix
    #pragma unroll
    for (int j2 = 0; j2 < 4; ++j2) tl[tid * 4 + j2] += stripbase;
    __syncthreads();
    // tl[t] is now base[t]; seed cursors with base + column prefix
    __shared__ int cur[NBKMAX];
    for (int t = tid; t < nbk; t += 256)
        cur[t] = bh[(size_t)b * nbk + t] + tl[t];
    __syncthreads();
    int start = b * SBLK, end = min(m, start + SBLK);
    for (int j = start + tid; j < end; j += 256) {
        int e0 = e[j], e1 = e[m + j];
        int pos = atomicAdd(&cur[e0 >> SSH], 1);   // LDS atomic, ~1.6 colliders
        perm[pos] = make_int4(e0, e1, r[j], j);
    }
}

// K1: gather + scores + exp + segment atomicAdd over sorted edges.
// Body R7-VERBATIM (the only HW-validated load/consume pattern).
__global__ __launch_bounds__(256) void k_scores_perm(
    const ushort* __restrict__ qc, const ushort* __restrict__ kc,
    const int4* __restrict__ perm,
    float* __restrict__ s, float* __restrict__ seg, int m, int do_swz)
{
    int bid = blockIdx.x;
    if (do_swz) {                       // XCD-chunked (bijective: grid%8==0)
        int nb8 = gridDim.x >> 3;
        bid = (bid & 7) * nb8 + (bid >> 3);
    }
    int wave = (bid << 2) + (threadIdx.x >> 6);
    int lane = threadIdx.x & 63;
    int j0 = wave * EPW;
    if (j0 >= m) return;

    int rr[EPW], jo[EPW];
    uint4 qa[EPW], kb[EPW];
    #pragma unroll
    for (int t = 0; t < EPW; ++t) {
        int j = j0 + t;
        int4 p = (j < m) ? perm[j] : make_int4(0, 0, 0, -1);
        rr[t] = p.z;
        jo[t] = p.w;   // original edge index (or -1 = inactive)
        qa[t] = ((const uint4*)(qc + (size_t)p.x * (B * D)))[lane];
        kb[t] = ((const uint4*)(kc + (size_t)p.y * (B * D)))[lane];
    }
    __builtin_amdgcn_sched_barrier(0);

    #pragma unroll
    for (int t = 0; t < EPW; ++t) {
        float p = dot16(qa[t], kb[t]);
        p += __shfl_xor(p, 1);
        p += __shfl_xor(p, 2);
        float ex = __expf(p * 0.0625f);     // /sqrt(256), no max shift
        if ((lane & 3) == 0 && jo[t] >= 0) {
            int bb = lane >> 5;
            int h  = (lane >> 2) & 7;
            s[((size_t)bb * m + jo[t]) * NH + h] = ex;
            atomicAdd(&seg[((size_t)rr[t] * B + bb) * NH + h], ex);
        }
    }
}

// K1-direct: original-order fallback (R7-verbatim).
__global__ __launch_bounds__(256) void k_scores_fused(
    const ushort* __restrict__ qc, const ushort* __restrict__ kc,
    const int* __restrict__ e, const int* __restrict__ r,
    float* __restrict__ s, float* __restrict__ seg, int m)
{
    int wave = (int)((blockIdx.x * blockDim.x + threadIdx.x) >> 6);
    int lane = threadIdx.x & 63;
    int j0 = wave * EPW;
    if (j0 >= m) return;

    int e0[EPW], e1[EPW], rr[EPW];
    #pragma unroll
    for (int t = 0; t < EPW; ++t) {
        int j = j0 + t;
        int ok = (j < m);
        e0[t] = ok ? e[j]     : 0;
        e1[t] = ok ? e[m + j] : 0;
        rr[t] = ok ? r[j]     : 0;
    }
    uint4 qa[EPW], kb[EPW];
    #pragma unroll
    for (int t = 0; t < EPW; ++t) {
        qa[t] = ((const uint4*)(qc + (size_t)e0[t] * (B * D)))[lane];
        kb[t] = ((const uint4*)(kc + (size_t)e1[t] * (B * D)))[lane];
    }
    __builtin_amdgcn_sched_barrier(0);
    #pragma unroll
    for (int t = 0; t < EPW; ++t) {
        float p = dot16(qa[t], kb[t]);
        p += __shfl_xor(p, 1);
        p += __shfl_xor(p, 2);
        float ex = __expf(p * 0.0625f);
        if ((lane & 3) == 0 && (j0 + t) < m) {
            int bb = lane >> 5;
            int h  = (lane >> 2) & 7;
            s[((size_t)bb * m + (j0 + t)) * NH + h] = ex;
            atomicAdd(&seg[((size_t)rr[t] * B + bb) * NH + h], ex);
        }
    }
}

// fp32 fallback (ws too small for bf16 buffers).
__global__ __launch_bounds__(256) void k_scores_fused_f32(
    const float* __restrict__ q, const float* __restrict__ k,
    const int* __restrict__ e, const int* __restrict__ r,
    float* __restrict__ s, float* __restrict__ seg, int n, int m)
{
    int wave = (int)((blockIdx.x * blockDim.x + threadIdx.x) >> 6);
    int lane = threadIdx.x & 63;
    int j0 = wave * EPW;
    if (j0 >= m) return;
    int e0[EPW], e1[EPW], rr[EPW];
    #pragma unroll
    for (int t = 0; t < EPW; ++t) {
        int j = j0 + t; int ok = (j < m);
        e0[t] = ok ? e[j] : 0; e1[t] = ok ? e[m + j] : 0; rr[t] = ok ? r[j] : 0;
    }
    float4 qa[B][EPW], kb[B][EPW];
    #pragma unroll
    for (int bb = 0; bb < B; ++bb)
        #pragma unroll
        for (int t = 0; t < EPW; ++t) {
            qa[bb][t] = ((const float4*)(q + ((size_t)bb * n + e0[t]) * D))[lane];
            kb[bb][t] = ((const float4*)(k + ((size_t)bb * n + e1[t]) * D))[lane];
        }
    #pragma unroll
    for (int bb = 0; bb < B; ++bb)
        #pragma unroll
        for (int t = 0; t < EPW; ++t) {
            float4 A = qa[bb][t], K4 = kb[bb][t];
            float p = A.x * K4.x + A.y * K4.y + A.z * K4.z + A.w * K4.w;
            p += __shfl_xor(p, 1); p += __shfl_xor(p, 2); p += __shfl_xor(p, 4);
            float ex = __expf(p * 0.0625f);
            if ((lane & 7) == 0 && (j0 + t) < m) {
                int h = lane >> 3;
                s[((size_t)bb * m + (j0 + t)) * NH + h] = ex;
                atomicAdd(&seg[((size_t)rr[t] * B + bb) * NH + h], ex);
            }
        }
}

// K2: one thread per (bb, edge). out = ex / (seg + eps), float4 in-place.
__global__ __launch_bounds__(256) void k_norm(
    float* __restrict__ s, const int* __restrict__ r,
    const float* __restrict__ seg, int m)
{
    int i = blockIdx.x * blockDim.x + threadIdx.x;
    int total = B * m;
    if (i >= total) return;
    int bb = (i >= m) ? 1 : 0;
    int j  = i - bb * m;
    const float4* sg = (const float4*)(seg + ((size_t)r[j] * B + bb) * NH);
    float4* sp = (float4*)(s + (size_t)i * NH);
    float4 d0 = sg[0], d1 = sg[1];
    float4 x0 = sp[0], x1 = sp[1];
    x0.x = __fdividef(x0.x, d0.x + 1e-16f);
    x0.y = __fdividef(x0.y, d0.y + 1e-16f);
    x0.z = __fdividef(x0.z, d0.z + 1e-16f);
    x0.w = __fdividef(x0.w, d0.w + 1e-16f);
    x1.x = __fdividef(x1.x, d1.x + 1e-16f);
    x1.y = __fdividef(x1.y, d1.y + 1e-16f);
    x1.z = __fdividef(x1.z, d1.z + 1e-16f);
    x1.w = __fdividef(x1.w, d1.w + 1e-16f);
    sp[0] = x0; sp[1] = x1;
}

extern "C" void kernel_launch(void* const* d_in, const int* in_sizes, int n_in,
                              void* d_out, int out_size, void* d_ws, size_t ws_size,
                              hipStream_t stream) {
    const float* q = (const float*)d_in[0];
    const float* k = (const float*)d_in[1];
    const int*   e = (const int*)d_in[2];
    const int*   r = (const int*)d_in[3];
    float* s = (float*)d_out;

    int n = in_sizes[0] / (B * D);          // 20000
    int m = in_sizes[3];                    // 320000
    int nbk  = (n + (1 << SSH) - 1) >> SSH; // 625 buckets (32 nodes each)
    int nch  = (m + SBLK - 1) / SBLK;       // 313 chunks
    int segN = n * B * NH;                  // 320000 floats

    // ws layout: seg | qc | kc | perm | bh | tot
    size_t seg_bytes  = (size_t)segN * sizeof(float);                // 1.28 MB
    size_t row_bytes  = (size_t)n * B * D * sizeof(unsigned short);  // 20.48 MB
    size_t perm_bytes = (size_t)m * sizeof(int4);                    // 5.12 MB
    size_t bh_bytes   = (size_t)nch * nbk * sizeof(int);             // ~0.8 MB
    size_t tb_bytes   = NBKMAX * sizeof(int);                        // 4 KB

    float*  seg  = (float*)d_ws;
    ushort* qc   = (ushort*)((char*)d_ws + seg_bytes);
    ushort* kc   = (ushort*)((char*)d_ws + seg_bytes + row_bytes);
    int4*   perm = (int4*)((char*)d_ws + seg_bytes + 2 * row_bytes);
    int*    bh   = (int*)((char*)d_ws + seg_bytes + 2 * row_bytes + perm_bytes);
    int*    tot  = (int*)((char*)bh + bh_bytes);

    bool use_bf16 = ws_size >= (seg_bytes + 2 * row_bytes);
    bool use_sort = use_bf16 && nbk <= NBKMAX && nch <= NCHMAX &&
                    ws_size >= (seg_bytes + 2 * row_bytes + perm_bytes +
                                bh_bytes + tb_bytes);

    int nblocks = (B * m + 255) / 256;
    int nwaves  = (m + EPW - 1) / EPW;
    int sblocks = (nwaves + 3) / 4;

    if (use_bf16) {
        int cblocks = (n * B * 32 + 255) / 256;
        k_conv<<<cblocks, 256, 0, stream>>>(q, k, (uint4*)qc, (uint4*)kc,
                                            seg, segN, n);
        if (use_sort) {
            k_hist2<<<nch, 256, 0, stream>>>(e, bh, m, nbk);
            k_colscan<<<nbk, NCHMAX, 0, stream>>>(bh, tot, nch, nbk);
            k_scatter2<<<nch, 256, 0, stream>>>(e, r, bh, tot, perm, m, nbk);
            int do_swz = (sblocks % 8 == 0) ? 1 : 0;
            k_scores_perm<<<sblocks, 256, 0, stream>>>(qc, kc, perm, s, seg, m, do_swz);
        } else {
            k_scores_fused<<<sblocks, 256, 0, stream>>>(qc, kc, e, r, s, seg, m);
        }
    } else {
        hipMemsetAsync(d_ws, 0, seg_bytes, stream);
        k_scores_fused_f32<<<sblocks, 256, 0, stream>>>(q, k, e, r, s, seg, n, m);
    }
    k_norm<<<nblocks, 256, 0, stream>>>(s, r, seg, m);
}